// Round 7
// baseline (909.199 us; speedup 1.0000x reference)
//
#include <hip/hip_runtime.h>
#include <hip/hip_bf16.h>

using f32x4 = __attribute__((ext_vector_type(4))) float;
using s16x8 = __attribute__((ext_vector_type(8))) short;

#define DEVFN static __device__ __forceinline__

static constexpr int NCOL = 256;
static constexpr int MROWS = 8192;
static constexpr int BM = 16;              // one MFMA m-tile per block
static constexpr int THREADS = 256;        // 4 waves, each owns 64 cols
static constexpr int NT2 = MROWS / BM;     // 512 m-tiles

DEVFN unsigned short f2bf(float f) {
  union { float f; unsigned u; } x; x.f = f;
  unsigned u = x.u;
  u += 0x7fffu + ((u >> 16) & 1u);   // RNE
  return (unsigned short)(u >> 16);
}

DEVFN s16x8 pack8(f32x4 v0, f32x4 v1) {
  union { s16x8 v; __hip_bfloat162 h[4]; } pk;
  pk.h[0] = __float22bfloat162_rn(float2{v0[0], v0[1]});
  pk.h[1] = __float22bfloat162_rn(float2{v0[2], v0[3]});
  pk.h[2] = __float22bfloat162_rn(float2{v1[0], v1[1]});
  pk.h[3] = __float22bfloat162_rn(float2{v1[2], v1[3]});
  return pk.v;
}

// C[M,256] = A[M,K] @ B[K,256], barrier-free / LDS-free, 16-row tiles.
//  A f32 row-major; all 4 waves load IDENTICAL A-fragment addresses (L1
//  broadcast), packed to bf16 via v_cvt_pk at use.
//  B bf16 P8 layout: elem (k,j) at ((k>>3)*256+j)*8+(k&7); wave wn reads only
//  its 64-col slice -> every B element read once per block.
//  Even/odd register double-buffer (4 A + 8 B dwordx4 loads per k=64 step),
//  no branches in loop (clamped prefetch), no barriers, no LDS.
//  KS-way split-K. EPI 0: f32 partials Cpart[kh][M][256]. EPI 1 (KS==1):
//  direct P8 bf16 output.
template<int KS, int EPI>
__global__ __launch_bounds__(THREADS, 4)
void gemm_sl(const float* __restrict__ A, int Kfull,
             const unsigned short* __restrict__ Bp8,
             float* __restrict__ Cpart, unsigned short* __restrict__ Pout)
{
  const int nwg = NT2 * KS;
  const int q = nwg / 8;
  const int logical = (blockIdx.x & 7) * q + (blockIdx.x >> 3);  // XCD-chunked
  const int kh = logical / NT2;
  const int tile = logical % NT2;

  const int klen = Kfull / KS;
  const int nt = klen / 64;            // even for all our K
  const int k0 = kh * klen;
  const int tid = threadIdx.x;
  const int lane = tid & 63;
  const int wn = tid >> 6;             // 0..3: cols wn*64..+64
  const int lr = lane & 15, lg = lane >> 4;

  // A: row tile*16 + lr, k chunk lg*8 (+32 for second k-half)
  const float* Ap = A + (size_t)(tile * BM + lr) * Kfull + k0 + lg * 8;
  // B: shorts base for (k-group k0/8 + lg, col wn*64 + lr)
  const unsigned short* Bb = Bp8 + (((size_t)(k0 >> 3) + lg) * 256 + wn * 64 + lr) * 8;

  f32x4 ra[2][4];
  s16x8 rb[2][8];
  f32x4 acc[4] = {};

#define LDA(BUF, T)                                                            \
  { const float* p = Ap + (size_t)(T) * 64;                                    \
    ra[BUF][0] = *(const f32x4*)p;        ra[BUF][1] = *(const f32x4*)(p + 4); \
    ra[BUF][2] = *(const f32x4*)(p + 32); ra[BUF][3] = *(const f32x4*)(p + 36); }
#define LDB(BUF, T)                                                            \
  { const unsigned short* p = Bb + (size_t)(T) * 16384;                        \
    _Pragma("unroll")                                                          \
    for (int s = 0; s < 2; ++s)                                                \
      _Pragma("unroll")                                                        \
      for (int c = 0; c < 4; ++c)                                              \
        rb[BUF][s * 4 + c] = *(const s16x8*)(p + s * 8192 + c * 128); }
#define COMP(BUF)                                                              \
  { s16x8 a0 = pack8(ra[BUF][0], ra[BUF][1]);                                  \
    s16x8 a1 = pack8(ra[BUF][2], ra[BUF][3]);                                  \
    _Pragma("unroll")                                                          \
    for (int c = 0; c < 4; ++c)                                                \
      acc[c] = __builtin_amdgcn_mfma_f32_16x16x32_bf16(a0, rb[BUF][c], acc[c], 0, 0, 0); \
    _Pragma("unroll")                                                          \
    for (int c = 0; c < 4; ++c)                                                \
      acc[c] = __builtin_amdgcn_mfma_f32_16x16x32_bf16(a1, rb[BUF][4 + c], acc[c], 0, 0, 0); }

  LDA(0, 0); LDB(0, 0);
  for (int t = 0; t < nt; t += 2) {
    const int t1 = (t + 1 < nt) ? t + 1 : nt - 1;
    const int t2 = (t + 2 < nt) ? t + 2 : nt - 2;
    LDA(1, t1); LDB(1, t1);
    COMP(0);
    LDA(0, t2); LDB(0, t2);
    COMP(1);
  }
#undef LDA
#undef LDB
#undef COMP

  // C/D layout: col = lane&15, row = (lane>>4)*4 + reg
  const int r0 = tile * BM + lg * 4;
  if constexpr (EPI == 0) {
    float* Co = Cpart + (size_t)kh * MROWS * NCOL;
#pragma unroll
    for (int c = 0; c < 4; ++c) {
      const int col = wn * 64 + c * 16 + lr;
#pragma unroll
      for (int r = 0; r < 4; ++r)
        Co[(size_t)(r0 + r) * NCOL + col] = acc[c][r];
    }
  } else {
#pragma unroll
    for (int c = 0; c < 4; ++c) {
      const int col = wn * 64 + c * 16 + lr;
      ushort4 u;
      u.x = f2bf(acc[c][0]); u.y = f2bf(acc[c][1]);
      u.z = f2bf(acc[c][2]); u.w = f2bf(acc[c][3]);
      *(ushort4*)&Pout[((size_t)(r0 >> 3) * 256 + col) * 8 + (r0 & 7)] = u;
    }
  }
}

// ---- small conversion / reduce kernels ---------------------------------

// f32 [K][256] -> P8 bf16
__global__ void k_convert_p8(const float* __restrict__ W, int K,
                             unsigned short* __restrict__ outp) {
  int tid = blockIdx.x * blockDim.x + threadIdx.x;
  if (tid >= K * NCOL / 4) return;
  int j = tid & (NCOL - 1);
  int i0 = (tid >> 8) << 2;
  unsigned short u[4];
#pragma unroll
  for (int r = 0; r < 4; ++r) u[r] = f2bf(W[(size_t)(i0 + r) * NCOL + j]);
  size_t off = ((size_t)(i0 >> 3) * NCOL + j) * 8 + (i0 & 7);
  *(ushort4*)&outp[off] = make_ushort4(u[0], u[1], u[2], u[3]);
}

// sum 2 partials, optional per-row filter scale, write P8 bf16
__global__ void k_reduce_p8(const float* __restrict__ P, const float* __restrict__ filt,
                            unsigned short* __restrict__ outp) {
  int tid = blockIdx.x * blockDim.x + threadIdx.x;
  int j = tid & (NCOL - 1);
  int i0 = (tid >> 8) << 2;
  unsigned short u[4];
#pragma unroll
  for (int r = 0; r < 4; ++r) {
    size_t o = (size_t)(i0 + r) * NCOL + j;
    float v = P[o] + P[(size_t)MROWS * NCOL + o];
    if (filt) v *= filt[i0 + r];
    u[r] = f2bf(v);
  }
  size_t off = ((size_t)(i0 >> 3) * NCOL + j) * 8 + (i0 & 7);
  *(ushort4*)&outp[off] = make_ushort4(u[0], u[1], u[2], u[3]);
}

// sum 2 partials, relu, write row-major f32 (A operand of next GEMM)
__global__ void k_reduce_relu(const float* __restrict__ P, float* __restrict__ h1f) {
  size_t o = (size_t)(blockIdx.x * blockDim.x + threadIdx.x) * 4;
  float4 a = *(const float4*)&P[o];
  float4 b = *(const float4*)&P[(size_t)MROWS * NCOL + o];
  float4 v;
  v.x = fmaxf(a.x + b.x, 0.f);
  v.y = fmaxf(a.y + b.y, 0.f);
  v.z = fmaxf(a.z + b.z, 0.f);
  v.w = fmaxf(a.w + b.w, 0.f);
  *(float4*)&h1f[o] = v;
}

// sum 2 partials, write f32 (final output)
__global__ void k_reduce_f32(const float* __restrict__ P, float* __restrict__ out) {
  size_t o = (size_t)(blockIdx.x * blockDim.x + threadIdx.x) * 4;
  float4 a = *(const float4*)&P[o];
  float4 b = *(const float4*)&P[(size_t)MROWS * NCOL + o];
  float4 v; v.x = a.x + b.x; v.y = a.y + b.y; v.z = a.z + b.z; v.w = a.w + b.w;
  *(float4*)&out[o] = v;
}

extern "C" void kernel_launch(void* const* d_in, const int* in_sizes, int n_in,
                              void* d_out, int out_size, void* d_ws, size_t ws_size,
                              hipStream_t stream) {
  const float* input = (const float*)d_in[0];
  const float* Wv    = (const float*)d_in[1];
  const float* Winv  = (const float*)d_in[2];
  const float* W1    = (const float*)d_in[3];
  const float* W2    = (const float*)d_in[4];
  const float* f1    = (const float*)d_in[5];
  const float* f2    = (const float*)d_in[6];
  float* out = (float*)d_out;

  char* ws = (char*)d_ws;
  float* part         = (float*)(ws);                         // 2 x 8MB
  unsigned short* t1p = (unsigned short*)(ws + 0x1000000);    // 4MB each, P8
  unsigned short* s1p = (unsigned short*)(ws + 0x1400000);
  unsigned short* t2p = (unsigned short*)(ws + 0x1800000);
  unsigned short* s2p = (unsigned short*)(ws + 0x1C00000);
  float* h1f          = (float*)(ws + 0x2000000);             // 8MB f32
  unsigned short* W1p = (unsigned short*)(ws + 0x2800000);    // 256KB
  unsigned short* W2p = (unsigned short*)(ws + 0x2840000);    // 128KB

  dim3 gT(THREADS);
  dim3 gBig(NT2 * 2);                                  // 1024 WGs, 4/CU
  dim3 gSmall(NT2);                                    // 512 WGs
  dim3 rT(256), rG(MROWS * NCOL / 4 / 256);            // 2048 WGs

  k_convert_p8<<<dim3(128), rT, 0, stream>>>(W1, 512, W1p);
  k_convert_p8<<<dim3(64),  rT, 0, stream>>>(W2, 256, W2p);

  // t1 = input @ W1                       (KS=1, direct P8 out)
  gemm_sl<1, 1><<<gSmall, gT, 0, stream>>>(input, 512, W1p, nullptr, t1p);
  // s1 = diag(f1).(Winv @ t1)
  gemm_sl<2, 0><<<gBig, gT, 0, stream>>>(Winv, 8192, t1p, part, nullptr);
  k_reduce_p8<<<rG, rT, 0, stream>>>(part, f1, s1p);
  // h1 = relu(Wv @ s1), f32
  gemm_sl<2, 0><<<gBig, gT, 0, stream>>>(Wv, 8192, s1p, part, nullptr);
  k_reduce_relu<<<rG, rT, 0, stream>>>(part, h1f);
  // t2 = h1 @ W2                          (KS=1, direct P8 out)
  gemm_sl<1, 1><<<gSmall, gT, 0, stream>>>(h1f, 256, W2p, nullptr, t2p);
  // s2 = diag(f2).(Winv @ t2)
  gemm_sl<2, 0><<<gBig, gT, 0, stream>>>(Winv, 8192, t2p, part, nullptr);
  k_reduce_p8<<<rG, rT, 0, stream>>>(part, f2, s2p);
  // out = Wv @ s2, f32
  gemm_sl<2, 0><<<gBig, gT, 0, stream>>>(Wv, 8192, s2p, part, nullptr);
  k_reduce_f32<<<rG, rT, 0, stream>>>(part, out);
}

// Round 8
// 430.237 us; speedup vs baseline: 2.1133x; 2.1133x over previous
//
#include <hip/hip_runtime.h>
#include <hip/hip_bf16.h>

using f32x4 = __attribute__((ext_vector_type(4))) float;
using s16x8 = __attribute__((ext_vector_type(8))) short;

#define DEVFN static __device__ __forceinline__

static constexpr int NCOL = 256;
static constexpr int MROWS = 8192;
static constexpr int BM = 64;
static constexpr int BK = 128;
static constexpr int THREADS = 512;       // 8 waves: wm(2) x wn(4)
static constexpr int NTILE = MROWS / BM;  // 128

DEVFN unsigned short f2bf(float f) {
  union { float f; unsigned u; } x; x.f = f;
  unsigned u = x.u;
  u += 0x7fffu + ((u >> 16) & 1u);   // RNE
  return (unsigned short)(u >> 16);
}

DEVFN s16x8 pack8(f32x4 v0, f32x4 v1) {
  union { s16x8 v; __hip_bfloat162 h[4]; } pk;
  pk.h[0] = __float22bfloat162_rn(float2{v0[0], v0[1]});
  pk.h[1] = __float22bfloat162_rn(float2{v0[2], v0[3]});
  pk.h[2] = __float22bfloat162_rn(float2{v1[0], v1[1]});
  pk.h[3] = __float22bfloat162_rn(float2{v1[2], v1[3]});
  return pk.v;
}

DEVFN void async16(void* lds, const void* g) {
  __builtin_amdgcn_global_load_lds((const __attribute__((address_space(1))) unsigned*)g,
                                   (__attribute__((address_space(3))) unsigned*)lds,
                                   16, 0, 0);
}

// C[M,256] = A[M,K] @ B[K,256], BM=64, BK=128, always writes f32 partials
// Cpart[kh][M][256] (kh = 0..KS-1).
//  !ABLK: A f32 row-major; reg-staged (issue loads early, cvt once,
//         swizzled ds_write after MFMAs); WB: also emit blocked bf16 copy
//         [mtile][ktile][64][128] (coalesced 32B/thread stores).
//  ABLK:  A blocked bf16; staged via global_load_lds (pre-swizzled source,
//         linear LDS dest).
//  LDS: 2 x 16KB bf16 A tile, chunk^(row&15) XOR-swizzle -> 2-way-free reads.
//  B bf16 P8 layout: elem(k,j) at ((k>>3)*256+j)*8+(k&7); streamed
//  global->reg one 16-VGPR group ahead (monotonic pointer), L2-resident.
template<bool ABLK, int KS, bool WB>
__global__ __launch_bounds__(THREADS, 4)
void gemm_m(const void* __restrict__ Aany, int Kfull,
            const unsigned short* __restrict__ Bp8,
            float* __restrict__ Cpart, unsigned short* __restrict__ Awb)
{
  __shared__ __align__(16) unsigned short As[2][BM * BK];   // 2 x 16KB

  const int nwg = NTILE * KS, q = nwg / 8;
  const int logical = (blockIdx.x & 7) * q + (blockIdx.x >> 3);  // XCD-chunked
  const int kh = logical >> 7;          // / NTILE
  const int tile = logical & 127;       // % NTILE
  const int klen = Kfull / KS;
  const int nt = klen / BK;
  const int k0 = kh * klen;
  const int tid = threadIdx.x, lane = tid & 63;
  const int wm = (tid >> 6) >> 2;       // 0..1 : rows wm*32..+32
  const int wn = (tid >> 6) & 3;        // 0..3 : cols wn*64..+64
  const int lr = lane & 15, lg = lane >> 4;
  const int srow = tid >> 3, sseg = tid & 7;   // f32 stage: row, 16-float seg

  const float* Af32 = (const float*)Aany;
  const unsigned short* Abf = (const unsigned short*)Aany;
  const int ktiles = Kfull >> 7;

  f32x4 rv[4];
  auto loadA = [&](int t) {             // issue 64B of f32 per thread
    const float* p = Af32 + (size_t)(tile * BM + srow) * Kfull + k0 + t * BK + sseg * 16;
    rv[0] = *(const f32x4*)p;       rv[1] = *(const f32x4*)(p + 4);
    rv[2] = *(const f32x4*)(p + 8); rv[3] = *(const f32x4*)(p + 12);
  };
  auto putA = [&](int buf, int t) {     // cvt once + swizzled LDS write (+WB)
    s16x8 p0 = pack8(rv[0], rv[1]), p1 = pack8(rv[2], rv[3]);
    const int kc0 = sseg * 2;
    *(s16x8*)&As[buf][srow * 128 + (((kc0    ) ^ (srow & 15)) << 3)] = p0;
    *(s16x8*)&As[buf][srow * 128 + (((kc0 + 1) ^ (srow & 15)) << 3)] = p1;
    if constexpr (WB) {
      unsigned short* w = Awb + ((size_t)tile * ktiles + (k0 >> 7) + t) * 8192
                        + srow * 128 + sseg * 16;
      *(s16x8*)w = p0; *(s16x8*)(w + 8) = p1;
    }
  };
  auto stageBf = [&](int buf, int t) {  // blocked bf16 -> LDS, pre-swizzled src
    const unsigned short* base = Abf + ((size_t)tile * ktiles + (k0 >> 7) + t) * 8192;
#pragma unroll
    for (int o = 0; o < 2; ++o) {
      const int bs = o * 8192 + tid * 16;          // linear dest byte slot
      const int row = bs >> 8, ch = (bs >> 4) & 15;
      async16(&As[buf][o * 4096 + tid * 8], base + row * 128 + ((ch ^ (row & 15)) << 3));
    }
  };

  // B streaming: per-lane base; group (t,s) at +(t*4+s)*8192 shorts
  const unsigned short* bptr = Bp8 + ((size_t)(k0 >> 3) + lg) * 2048
                             + (size_t)(wn * 64 + lr) * 8;
  s16x8 bb[2][4];
  auto ldb = [&](const unsigned short* p, s16x8* d) {
#pragma unroll
    for (int fn = 0; fn < 4; ++fn) d[fn] = *(const s16x8*)(p + fn * 128);
  };

  f32x4 acc[2][4] = {};

  if constexpr (ABLK) { stageBf(0, 0); } else { loadA(0); putA(0, 0); }
  ldb(bptr, bb[0]);                      // group (t=0, s=0)
  bptr += 8192;
  __syncthreads();

  int cur = 0;
  for (int t = 0; t < nt; ++t) {
    const bool pre = (t + 1 < nt);
    if (pre) { if constexpr (ABLK) stageBf(cur ^ 1, t + 1); else loadA(t + 1); }
#pragma unroll
    for (int s = 0; s < 4; ++s) {
      if (pre || s < 3) { ldb(bptr, bb[(s + 1) & 1]); bptr += 8192; }
      s16x8 a0, a1;
      {
        const int r0 = wm * 32 + lr, kc = s * 4 + lg;
        a0 = *(const s16x8*)&As[cur][r0 * 128 + ((kc ^ (r0 & 15)) << 3)];
        const int r1 = r0 + 16;
        a1 = *(const s16x8*)&As[cur][r1 * 128 + ((kc ^ (r1 & 15)) << 3)];
      }
#pragma unroll
      for (int fn = 0; fn < 4; ++fn) {
        acc[0][fn] = __builtin_amdgcn_mfma_f32_16x16x32_bf16(a0, bb[s & 1][fn], acc[0][fn], 0, 0, 0);
        acc[1][fn] = __builtin_amdgcn_mfma_f32_16x16x32_bf16(a1, bb[s & 1][fn], acc[1][fn], 0, 0, 0);
      }
    }
    if constexpr (!ABLK) { if (pre) putA(cur ^ 1, t + 1); }
    __syncthreads();
    cur ^= 1;
  }

  // C/D layout: col = lane&15, row = (lane>>4)*4 + reg
  float* Co = Cpart + (size_t)kh * MROWS * NCOL;
#pragma unroll
  for (int fm = 0; fm < 2; ++fm) {
    const int row = tile * BM + wm * 32 + fm * 16 + lg * 4;
#pragma unroll
    for (int fn = 0; fn < 4; ++fn) {
      const int col = wn * 64 + fn * 16 + lr;
#pragma unroll
      for (int r = 0; r < 4; ++r)
        Co[(size_t)(row + r) * NCOL + col] = acc[fm][fn][r];
    }
  }
}

// ---- conversion / reduce kernels ---------------------------------------

// f32 [K][256] -> P8 bf16 (weights)
__global__ void k_convert_p8(const float* __restrict__ W, int K,
                             unsigned short* __restrict__ outp) {
  int tid = blockIdx.x * blockDim.x + threadIdx.x;
  if (tid >= K * NCOL / 4) return;
  int j = tid & (NCOL - 1);
  int i0 = (tid >> 8) << 2;
  unsigned short u[4];
#pragma unroll
  for (int r = 0; r < 4; ++r) u[r] = f2bf(W[(size_t)(i0 + r) * NCOL + j]);
  size_t off = ((size_t)(i0 >> 3) * NCOL + j) * 8 + (i0 & 7);
  *(ushort4*)&outp[off] = make_ushort4(u[0], u[1], u[2], u[3]);
}

// sum NS partials; MODE 0: P8 bf16 (optional per-row filt); MODE 1: relu ->
// blocked bf16 [m/64][c/128][64][128] (K=256); MODE 2: f32 row-major.
template<int NS, int MODE>
__global__ void k_reduce(const float* __restrict__ P, const float* __restrict__ filt,
                         void* __restrict__ Out) {
  int tid = blockIdx.x * blockDim.x + threadIdx.x;
  if constexpr (MODE == 0) {
    int j = tid & (NCOL - 1);
    int i0 = (tid >> 8) << 2;
    unsigned short u[4];
#pragma unroll
    for (int r = 0; r < 4; ++r) {
      size_t o = (size_t)(i0 + r) * NCOL + j;
      float v = 0.f;
#pragma unroll
      for (int h = 0; h < NS; ++h) v += P[(size_t)h * MROWS * NCOL + o];
      if (filt) v *= filt[i0 + r];
      u[r] = f2bf(v);
    }
    size_t off = ((size_t)(i0 >> 3) * NCOL + j) * 8 + (i0 & 7);
    *(ushort4*)&((unsigned short*)Out)[off] = make_ushort4(u[0], u[1], u[2], u[3]);
  } else {
    size_t o = (size_t)tid * 4;
    float4 v = *(const float4*)&P[o];
#pragma unroll
    for (int h = 1; h < NS; ++h) {
      float4 b = *(const float4*)&P[(size_t)h * MROWS * NCOL + o];
      v.x += b.x; v.y += b.y; v.z += b.z; v.w += b.w;
    }
    if constexpr (MODE == 1) {
      const int m = (int)(o >> 8), c = (int)(o & 255);
      ushort4 u;
      u.x = f2bf(fmaxf(v.x, 0.f)); u.y = f2bf(fmaxf(v.y, 0.f));
      u.z = f2bf(fmaxf(v.z, 0.f)); u.w = f2bf(fmaxf(v.w, 0.f));
      size_t off = ((size_t)(m >> 6) * 2 + (c >> 7)) * 8192 + (m & 63) * 128 + (c & 127);
      *(ushort4*)&((unsigned short*)Out)[off] = u;
    } else {
      *(float4*)&((float*)Out)[o] = v;
    }
  }
}

extern "C" void kernel_launch(void* const* d_in, const int* in_sizes, int n_in,
                              void* d_out, int out_size, void* d_ws, size_t ws_size,
                              hipStream_t stream) {
  const float* input = (const float*)d_in[0];
  const float* Wv    = (const float*)d_in[1];
  const float* Winv  = (const float*)d_in[2];
  const float* W1    = (const float*)d_in[3];
  const float* W2    = (const float*)d_in[4];
  const float* f1    = (const float*)d_in[5];
  const float* f2    = (const float*)d_in[6];
  float* out = (float*)d_out;

  char* ws = (char*)d_ws;
  unsigned short* WvB   = (unsigned short*)(ws);                 // 128MB blocked bf16
  unsigned short* WinvB = (unsigned short*)(ws + 0x8000000);     // 128MB
  float* part           = (float*)(ws + 0x10000000);             // 32MB (4 partials)
  unsigned short* t1p   = (unsigned short*)(ws + 0x12000000);    // 4MB each, P8
  unsigned short* s1p   = (unsigned short*)(ws + 0x12400000);
  unsigned short* t2p   = (unsigned short*)(ws + 0x12800000);
  unsigned short* s2p   = (unsigned short*)(ws + 0x12C00000);
  unsigned short* h1b   = (unsigned short*)(ws + 0x13000000);    // 4MB blocked bf16
  unsigned short* W1p   = (unsigned short*)(ws + 0x13400000);    // 256KB
  unsigned short* W2p   = (unsigned short*)(ws + 0x13440000);    // 128KB

  dim3 gT(THREADS);
  dim3 g4(NTILE * 4), g2(NTILE * 2);                   // 512 / 256 WGs
  dim3 rT(256), rG(MROWS * NCOL / 4 / 256);            // 2048 WGs

  k_convert_p8<<<dim3(128), rT, 0, stream>>>(W1, 512, W1p);
  k_convert_p8<<<dim3(64),  rT, 0, stream>>>(W2, 256, W2p);

  // t1 = input @ W1        (f32 A, K=512, KS=4 -> nt=1)
  gemm_m<false, 4, false><<<g4, gT, 0, stream>>>((const void*)input, 512, W1p, part, nullptr);
  k_reduce<4, 0><<<rG, rT, 0, stream>>>(part, nullptr, t1p);
  // s1 = diag(f1).(Winv @ t1)   (f32 A + blocked-bf16 writeback)
  gemm_m<false, 4, true><<<g4, gT, 0, stream>>>((const void*)Winv, 8192, t1p, part, WinvB);
  k_reduce<4, 0><<<rG, rT, 0, stream>>>(part, f1, s1p);
  // h1 = relu(Wv @ s1)          (f32 A + blocked-bf16 writeback)
  gemm_m<false, 4, true><<<g4, gT, 0, stream>>>((const void*)Wv, 8192, s1p, part, WvB);
  k_reduce<4, 1><<<rG, rT, 0, stream>>>(part, nullptr, h1b);
  // t2 = h1 @ W2            (blocked bf16 A, K=256, KS=2 -> nt=1)
  gemm_m<true, 2, false><<<g2, gT, 0, stream>>>((const void*)h1b, 256, W2p, part, nullptr);
  k_reduce<2, 0><<<rG, rT, 0, stream>>>(part, nullptr, t2p);
  // s2 = diag(f2).(Winv @ t2)   (blocked bf16 A)
  gemm_m<true, 4, false><<<g4, gT, 0, stream>>>((const void*)WinvB, 8192, t2p, part, nullptr);
  k_reduce<4, 0><<<rG, rT, 0, stream>>>(part, f2, s2p);
  // out = Wv @ s2               (blocked bf16 A, f32 out)
  gemm_m<true, 4, false><<<g4, gT, 0, stream>>>((const void*)WvB, 8192, s2p, part, nullptr);
  k_reduce<4, 2><<<rG, rT, 0, stream>>>(part, nullptr, out);
}